// Round 2
// baseline (334.105 us; speedup 1.0000x reference)
//
#include <hip/hip_runtime.h>
#include <math.h>

#define IH 2048
#define IW 2048
#define NBATCH 8
#define TILE 64
#define HALO 3
#define SROW 80          // s_img row stride in dwords (20 16B-blocks; swizzle-safe)
#define NROW 68          // s_nv row stride in dwords
#define ACT_TH 0.1f
#define IMP_TH 0.1f

// 1D Gaussian taps, sigma = 7/6, normalized (matches reference 2D outer product).
#define G0 0.0125602013f
#define G1 0.0788279697f
#define G2 0.2372960895f
#define G3 0.3426314790f

__device__ __forceinline__ float fsqrt_f(float x) { return __builtin_amdgcn_sqrtf(x); }
__device__ __forceinline__ float frcp_f(float x)  { return __builtin_amdgcn_rcpf(x); }

// Swizzled dword index into s_img for logical (row, col).
// 16B-block index XORed with 2 row bits so the 4 row-group lanes of a wave
// (row step 4 -> 320 dwords === 0 mod 32) land in distinct bank groups.
__device__ __forceinline__ int simg_ix(int r, int c) {
    int m = (c >> 2) ^ ((r >> 2) & 3);      // m <= 17, ^3 -> <= 19 < 20 blocks
    return r * SROW + (m << 2) + (c & 3);
}

// ---------------- Kernel 1: per-batch max --------------------------------
__global__ __launch_bounds__(256) void batch_max_kernel(
    const float* __restrict__ x, unsigned int* __restrict__ maxbits)
{
    const int b = blockIdx.y;
    const float4* p = (const float4*)(x + (size_t)b * (size_t)(IH * IW));
    const int n4 = IH * IW / 4;
    float m = 0.0f;
    for (int i = blockIdx.x * blockDim.x + threadIdx.x; i < n4;
         i += gridDim.x * blockDim.x) {
        float4 v = p[i];
        m = fmaxf(m, fmaxf(fmaxf(v.x, v.y), fmaxf(v.z, v.w)));
    }
#pragma unroll
    for (int s = 1; s < 64; s <<= 1) m = fmaxf(m, __shfl_xor(m, s));
    __shared__ float sm[4];
    const int lane = threadIdx.x & 63, wv = threadIdx.x >> 6;
    if (lane == 0) sm[wv] = m;
    __syncthreads();
    if (threadIdx.x == 0) {
        m = fmaxf(fmaxf(sm[0], sm[1]), fmaxf(sm[2], sm[3]));
        // x is uniform[0,1): non-negative, so uint-bit compare == float compare
        atomicMax(&maxbits[b], __float_as_uint(m));
    }
}

// ---------------- Kernel 2: fused normalize + block stats ----------------
// Register-blocked separable conv: each thread owns a 4-col x 4-row output
// patch. Per halo row: 3 aligned ds_read_b128 fetch the 12-wide window,
// h-conv runs in registers, vertical taps accumulate in ascending-k order
// (bit-identical to the sequential fmaf chain of the previous version).
__global__ __launch_bounds__(256, 4) void piqe_main_kernel(
    const float* __restrict__ x, const unsigned int* __restrict__ maxbits,
    float* __restrict__ contrib_sum, unsigned int* __restrict__ nhsa)
{
    __shared__ __align__(16) float s_img[70 * SROW];   // swizzled halo tile
    __shared__ __align__(16) float s_nv[64 * NROW];    // compact MSCN tile
    __shared__ float s_c;
    __shared__ unsigned int s_a;

    const int tid = threadIdx.x;
    const int b = blockIdx.z;
    const int ox = blockIdx.x * TILE;
    const int oy = blockIdx.y * TILE;
    const float* img0 = x + (size_t)b * (size_t)(IH * IW);
    const float scale = 255.0f / __uint_as_float(maxbits[b]);

    if (tid == 0) { s_c = 0.0f; s_a = 0u; }

    // Phase A: load 70x70 halo tile (edge-clamped), img = round(255*x/max)
    if (ox != 0 && oy != 0 && ox != IW - TILE && oy != IH - TILE) {
        // interior: no clamping needed
        const float* base = img0 + (size_t)(oy - HALO) * IW + (ox - HALO);
        for (int i = tid; i < 70 * 70; i += 256) {
            int r = i / 70, c = i - r * 70;
            s_img[simg_ix(r, c)] = rintf(base[r * IW + c] * scale);
        }
    } else {
        for (int i = tid; i < 70 * 70; i += 256) {
            int r = i / 70, c = i - r * 70;
            int gy = oy + r - HALO; gy = max(0, min(IH - 1, gy));
            int gx = ox + c - HALO; gx = max(0, min(IW - 1, gx));
            s_img[simg_ix(r, c)] = rintf(img0[(size_t)gy * IW + gx] * scale);
        }
    }
    __syncthreads();

    const float gk[7] = {G0, G1, G2, G3, G2, G1, G0};
    const int q = tid & 15;      // col group: output cols 4q..4q+3
    const int g = tid >> 4;      // row group: output rows 4g..4g+3

    // Phase B+C fused: stream 10 halo rows; h-conv in registers; vertical
    // taps accumulate into vm/vm2; finished rows go straight to s_nv.
    float vm[4][4], vm2[4][4], pv[4][4];
#pragma unroll
    for (int r = 0; r < 4; ++r)
#pragma unroll
        for (int c = 0; c < 4; ++c) { vm[r][c] = 0.0f; vm2[r][c] = 0.0f; }

#pragma unroll
    for (int jj = 0; jj < 10; ++jj) {
        const int row = 4 * g + jj;                 // halo row
        const int s = (row >> 2) & 3;
        const float4* rp = (const float4*)&s_img[row * SROW];
        float4 A = rp[q ^ s];
        float4 B = rp[(q + 1) ^ s];
        float4 C = rp[(q + 2) ^ s];
        float w[12] = {A.x, A.y, A.z, A.w, B.x, B.y, B.z, B.w,
                       C.x, C.y, C.z, C.w};         // halo cols 4q..4q+11

        float hm[4], h2[4];
#pragma unroll
        for (int c = 0; c < 4; ++c) {
            float m = 0.0f, m2 = 0.0f;
#pragma unroll
            for (int k = 0; k < 7; ++k) {
                float v = w[c + k];
                m = fmaf(gk[k], v, m);
                m2 = fmaf(gk[k] * v, v, m2);
            }
            hm[c] = m; h2[c] = m2;
        }
        if (jj >= 3 && jj <= 6) {                   // center pixels, rows 3..6
#pragma unroll
            for (int c = 0; c < 4; ++c) pv[jj - 3][c] = w[c + 3];
        }
#pragma unroll
        for (int r = 0; r < 4; ++r) {
            const int k = jj - r;                   // tap index, ascending per r
            if (k >= 0 && k < 7) {
#pragma unroll
                for (int c = 0; c < 4; ++c) {
                    vm[r][c]  = fmaf(gk[k], hm[c], vm[r][c]);
                    vm2[r][c] = fmaf(gk[k], h2[c], vm2[r][c]);
                }
            }
        }
        if (jj >= 6) {                              // output row r complete
            const int r = jj - 6;
            float o0, o1, o2, o3;
            {
                float m = vm[r][0];
                float sd = fsqrt_f(fabsf(vm2[r][0] - m * m));
                o0 = (pv[r][0] - m) * frcp_f(sd + 1.0f);
            }
            {
                float m = vm[r][1];
                float sd = fsqrt_f(fabsf(vm2[r][1] - m * m));
                o1 = (pv[r][1] - m) * frcp_f(sd + 1.0f);
            }
            {
                float m = vm[r][2];
                float sd = fsqrt_f(fabsf(vm2[r][2] - m * m));
                o2 = (pv[r][2] - m) * frcp_f(sd + 1.0f);
            }
            {
                float m = vm[r][3];
                float sd = fsqrt_f(fabsf(vm2[r][3] - m * m));
                o3 = (pv[r][3] - m) * frcp_f(sd + 1.0f);
            }
            *(float4*)&s_nv[(4 * g + r) * NROW + 4 * q] =
                make_float4(o0, o1, o2, o3);
        }
    }
    __syncthreads();

    // Phase D: per-16x16-block stats (identical op order to prior version).
    const int lane = tid & 63;
    const int wv = tid >> 6;
    const int blk = wv * 4 + (lane >> 4);
    const int L = lane & 15;
    const int bi = blk >> 2, bj = blk & 3;
    const float* np0 = &s_nv[(bi * 16) * NROW + bj * 16];

    float rv[16];
    {
        const float4* rp4 = (const float4*)(np0 + L * NROW);
        float4 r0 = rp4[0], r1 = rp4[1], r2 = rp4[2], r3 = rp4[3];
        rv[0] = r0.x; rv[1] = r0.y; rv[2]  = r0.z; rv[3]  = r0.w;
        rv[4] = r1.x; rv[5] = r1.y; rv[6]  = r1.z; rv[7]  = r1.w;
        rv[8] = r2.x; rv[9] = r2.y; rv[10] = r2.z; rv[11] = r2.w;
        rv[12] = r3.x; rv[13] = r3.y; rv[14] = r3.z; rv[15] = r3.w;
    }
    float s1 = 0.0f, s2 = 0.0f;
#pragma unroll
    for (int k = 0; k < 16; ++k) {
        float v = rv[k];
        s1 += v;
        s2 += v * v;
    }
    float c1 = rv[7] + rv[8];
    float c2 = rv[7] * rv[7] + rv[8] * rv[8];
    float u1 = s1 - rv[7] - rv[9];                   // sur: keep col 8, drop 7,9
    float u2 = s2 - rv[7] * rv[7] - rv[9] * rv[9];

    // Edge 11-window seg-std minima: lanes 0..3 of each block group
    float minstd = __builtin_inff();
    if (L < 4) {
        int offs, stp;
        if (L == 0)      { offs = 0;         stp = 1; }     // top row
        else if (L == 1) { offs = 15 * NROW; stp = 1; }     // bottom row
        else if (L == 2) { offs = 0;         stp = NROW; }  // left col
        else             { offs = 15;        stp = NROW; }  // right col
        float e[16];
#pragma unroll
        for (int k = 0; k < 16; ++k) e[k] = np0[offs + k * stp];
        float w1 = 0.0f, w2 = 0.0f;
#pragma unroll
        for (int k = 0; k < 6; ++k) { w1 += e[k]; w2 += e[k] * e[k]; }
#pragma unroll
        for (int i = 0; i < 11; ++i) {
            float var = (w2 - w1 * w1 * (1.0f / 6.0f)) * (1.0f / 5.0f);
            minstd = fminf(minstd, fsqrt_f(fmaxf(var, 0.0f)));
            if (i < 10) {
                w1 += e[i + 6] - e[i];
                w2 += e[i + 6] * e[i + 6] - e[i] * e[i];
            }
        }
    }

    // Butterfly reductions within each 16-lane group
#pragma unroll
    for (int m = 1; m < 16; m <<= 1) {
        s1 += __shfl_xor(s1, m);
        s2 += __shfl_xor(s2, m);
        c1 += __shfl_xor(c1, m);
        c2 += __shfl_xor(c2, m);
        u1 += __shfl_xor(u1, m);
        u2 += __shfl_xor(u2, m);
        minstd = fminf(minstd, __shfl_xor(minstd, m));
    }

    if (L == 0) {
        float bv = fmaxf((s2 - s1 * s1 * (1.0f / 256.0f)) * (1.0f / 255.0f), 0.0f);
        bool active = bv > ACT_TH;
        float cstd = fsqrt_f(fmaxf((c2 - c1 * c1 * (1.0f / 32.0f)) * (1.0f / 31.0f), 0.0f));
        float sstd = fsqrt_f(fmaxf((u2 - u1 * u1 * (1.0f / 224.0f)) * (1.0f / 223.0f), 0.0f));
        float csd = cstd * frcp_f(sstd);         // 0*rcp(0) -> NaN (matches ref 0/0)
        if (csd != csd) csd = 0.0f;              // jnp.where(isnan(csd), 0, csd)
        float sigma = fsqrt_f(bv);
        float beta = fabsf(sigma - csd) * frcp_f(fmaxf(sigma, csd));
        bool wnc = sigma > 2.0f * beta;          // NaN beta -> false (matches)
        bool impaired = minstd < IMP_TH;
        if (active) {
            float contrib = (impaired ? (1.0f - bv) : 0.0f) + (wnc ? bv : 0.0f);
            atomicAdd(&s_c, contrib);
            atomicAdd(&s_a, 1u);
        }
    }
    __syncthreads();
    if (tid == 0) {
        atomicAdd(&contrib_sum[b], s_c);
        atomicAdd(&nhsa[b], s_a);
    }
}

// ---------------- Kernel 3: final score ----------------------------------
__global__ void piqe_finish_kernel(const float* __restrict__ contrib_sum,
                                   const unsigned int* __restrict__ nhsa,
                                   float* __restrict__ out)
{
    int b = threadIdx.x;
    if (b < NBATCH)
        out[b] = (contrib_sum[b] + 1.0f) / (1.0f + (float)nhsa[b]) * 100.0f;
}

extern "C" void kernel_launch(void* const* d_in, const int* in_sizes, int n_in,
                              void* d_out, int out_size, void* d_ws, size_t ws_size,
                              hipStream_t stream)
{
    const float* x = (const float*)d_in[0];
    float* out = (float*)d_out;

    unsigned int* maxbits = (unsigned int*)d_ws;                    // 8 u32
    float* contrib = (float*)((char*)d_ws + 32);                    // 8 f32
    unsigned int* nhsa = (unsigned int*)((char*)d_ws + 64);         // 8 u32

    hipMemsetAsync(d_ws, 0, 96, stream);
    batch_max_kernel<<<dim3(128, NBATCH), 256, 0, stream>>>(x, maxbits);
    piqe_main_kernel<<<dim3(IW / TILE, IH / TILE, NBATCH), 256, 0, stream>>>(
        x, maxbits, contrib, nhsa);
    piqe_finish_kernel<<<1, 64, 0, stream>>>(contrib, nhsa, out);
}